// Round 1
// baseline (344.394 us; speedup 1.0000x reference)
//
#include <hip/hip_runtime.h>
#include <float.h>

// Shapes (fixed by the problem)
#define Bsz 2
#define Ssz 4096
#define Hsz 12
#define Gsz 64
#define Wsz 513            // W_LOC
#define Csz (Gsz + Wsz)    // 577 channels
#define ROW (Hsz * Csz)    // 6924 floats per (b,s) row
#define HALF 256           // (Wsz-1)/2
#define RPB 8              // rows per block
#define WIN (RPB + Wsz - 1) // 520-wide output window per block

// Workspace layout (floats)
#define PSUM_SZ ((size_t)Bsz * Ssz)   // 8192
#define GACC_SZ ((size_t)Bsz * Gsz)   // 128

// K1: fused h-sum + anti-diagonal accumulation, NO LDS staging.
// Block = 256 threads, 8 consecutive rows (same b since 8 | 4096).
// Thread t owns channels {t, t+256, t+512(<577)}. For each row it sums the
// 12 heads directly from global memory (each (h, channel-chunk) read is a
// fully coalesced 4B/lane stream), then accumulates:
//   c <  64 : per-thread register g (global channel c == t)
//   c >= 64 : LDS atomicAdd into win[(c-64)+r]  (races across rows are
//             possible since there is no per-row barrier -> atomics)
// Only two __syncthreads per block (win init / win flush). All 27 loads
// per row per thread are independent -> deep MLP, HBM-bound.
__global__ __launch_bounds__(256, 4) void k1_fused(
    const float* __restrict__ probs, const float* __restrict__ mask,
    float* __restrict__ psum, float* __restrict__ gacc)
{
    __shared__ float win[WIN];     // 2,080 B (no 27.7 KB row buffer anymore)
    const int t = threadIdx.x;
    const int row0 = blockIdx.x * RPB;
    const int b = row0 / Ssz;
    float g = 0.f;                 // thread t<64: global channel t

    for (int w = t; w < WIN; w += 256) win[w] = 0.f;
    __syncthreads();

    for (int r = 0; r < RPB; ++r) {
        const int row = row0 + r;
        const float* base = probs + (size_t)row * ROW;
        const float scale = (mask[row] < 0.f) ? 0.f : 1.f;

        float v0 = 0.f, v1 = 0.f, v2 = 0.f;
        #pragma unroll
        for (int h = 0; h < Hsz; ++h) {
            const float* hp = base + h * Csz;
            v0 += __builtin_nontemporal_load(hp + t);          // c = t
            v1 += __builtin_nontemporal_load(hp + t + 256);    // c = t+256
            if (t < Csz - 512)                                  // c = t+512 < 577
                v2 += __builtin_nontemporal_load(hp + t + 512);
        }
        v0 *= scale; v1 *= scale; v2 *= scale;

        if (t < Gsz) g += v0;                                  // global channel
        else atomicAdd(&win[(t - Gsz) + r], v0);               // local, c-64 = t-64
        atomicAdd(&win[(t + 256 - Gsz) + r], v1);              // local, c-64 = t+192
        if (t < Csz - 512)
            atomicAdd(&win[(t + 512 - Gsz) + r], v2);          // local, c-64 = t+448
    }
    __syncthreads();

    // flush the 520-wide window: i = (s0 - 256) + w
    const int i_base = (row0 - b * Ssz) - HALF;
    for (int w = t; w < WIN; w += 256) {
        const int i = i_base + w;
        if (i >= 0 && i < Ssz) atomicAdd(&psum[b * Ssz + i], win[w]);
    }
    if (t < Gsz) atomicAdd(&gacc[b * Gsz + t], g);
}

// K4: fused scatter (old k3) + per-batch max + scores + mask.
// grid = B, block = 1024 (16 waves). psum row staged in LDS; the 128-entry
// index-driven scatter is applied to the LDS copy (block b only touches its
// own row, so no cross-block hazard), then reduce + write outputs.
__global__ __launch_bounds__(1024) void k4_final(
    const float* __restrict__ psum, const float* __restrict__ thr_p,
    const int* __restrict__ loc_b, const int* __restrict__ loc_i,
    const int* __restrict__ glob_b, const int* __restrict__ glob_i,
    const float* __restrict__ gacc, int n_idx,
    float* __restrict__ out)
{
    const int b = blockIdx.x;
    const int t = threadIdx.x;
    __shared__ float sp[Ssz];      // 16 KB
    const float* p = psum + (size_t)b * Ssz;

    for (int i = t; i < Ssz; i += 1024) sp[i] = p[i];
    __syncthreads();

    // honor the index arrays: psum[loc_b,loc_i] += gacc[glob_b,glob_i]
    for (int k = t; k < n_idx; k += 1024)
        if (loc_b[k] == b)
            atomicAdd(&sp[loc_i[k]], gacc[glob_b[k] * Gsz + glob_i[k]]);
    __syncthreads();

    float m = -FLT_MAX;
    for (int i = t; i < Ssz; i += 1024) m = fmaxf(m, sp[i]);
    #pragma unroll
    for (int off = 32; off >= 1; off >>= 1) m = fmaxf(m, __shfl_down(m, off, 64));

    __shared__ float red[16];
    const int wave = t >> 6, lane = t & 63;
    if (lane == 0) red[wave] = m;
    __syncthreads();
    if (t == 0) {
        float mm = red[0];
        #pragma unroll
        for (int w = 1; w < 16; ++w) mm = fmaxf(mm, red[w]);
        red[0] = mm;
    }
    __syncthreads();
    const float mx = red[0];
    const float thr = fmaxf(1e-5f, thr_p[0]);

    for (int i = t; i < Ssz; i += 1024) {
        float sc = sp[i] / mx;                                    // divide: match ref rounding
        out[(size_t)Bsz * Ssz + (size_t)b * Ssz + i] = sc;        // scores (output 1)
        out[(size_t)b * Ssz + i] = (sc < thr) ? -10000.f : 0.f;   // mask (output 0)
    }
}

extern "C" void kernel_launch(void* const* d_in, const int* in_sizes, int n_in,
                              void* d_out, int out_size, void* d_ws, size_t ws_size,
                              hipStream_t stream)
{
    const float* mask  = (const float*)d_in[0];
    const float* probs = (const float*)d_in[1];
    const float* thr   = (const float*)d_in[2];
    // d_in[3] = max_num_global_attn_indices (hard-coded as Gsz)
    const int* loc_b  = (const int*)d_in[4];
    const int* loc_i  = (const int*)d_in[5];
    const int* glob_b = (const int*)d_in[6];
    const int* glob_i = (const int*)d_in[7];
    const int n_idx = in_sizes[4];

    float* psum = (float*)d_ws;
    float* gacc = psum + PSUM_SZ;
    float* out  = (float*)d_out;

    // zero psum + gacc (ws is poisoned 0xAA before every launch)
    hipMemsetAsync(psum, 0, (PSUM_SZ + GACC_SZ) * sizeof(float), stream);

    k1_fused<<<dim3(Bsz * Ssz / RPB), dim3(256), 0, stream>>>(probs, mask, psum, gacc);
    k4_final<<<dim3(Bsz), dim3(1024), 0, stream>>>(psum, thr, loc_b, loc_i,
                                                   glob_b, glob_i, gacc, n_idx, out);
}